// Round 3
// baseline (11788.511 us; speedup 1.0000x reference)
//
#include <hip/hip_runtime.h>

#define HH 1024
#define CC 56
#define TT 64
#define GRID 1024
#define NT 256
#define LEAVES 32
#define BPL (GRID / LEAVES)   // blocks per leaf = 32
#define NFLAG 8
#define AGENT __HIP_MEMORY_SCOPE_AGENT

__device__ __forceinline__ float wredsum(float v) {
#pragma unroll
  for (int m = 32; m; m >>= 1) v += __shfl_xor(v, m, 64);
  return v;
}

__device__ __forceinline__ float sigm(float x) { return 1.f / (1.f + __expf(-x)); }
__device__ __forceinline__ float ftanh(float x) {
  x = fminf(15.f, fmaxf(-15.f, x));
  float e = __expf(2.f * x);
  return (e - 1.f) / (e + 1.f);
}
__device__ __forceinline__ float dot4(float4 a, float4 b) {
  return fmaf(a.x, b.x, fmaf(a.y, b.y, fmaf(a.z, b.z, a.w * b.w)));
}

// two-level generation grid barrier, 8-line flag broadcast.
__device__ __forceinline__ void gbar(int* iws, int g, int b) {
  __syncthreads();
  if (threadIdx.x == 0) {
    int* leafc = iws + 256 + 32 * (b & (LEAVES - 1));
    if (__hip_atomic_fetch_add(leafc, 1, __ATOMIC_ACQ_REL, AGENT) == g * BPL - 1) {
      if (__hip_atomic_fetch_add(iws + 64, 1, __ATOMIC_ACQ_REL, AGENT) == g * LEAVES - 1) {
#pragma unroll
        for (int k = 0; k < NFLAG; ++k)
          __hip_atomic_store(iws + 2048 + 32 * k, g, __ATOMIC_RELEASE, AGENT);
      }
    }
    int* flag = iws + 2048 + 32 * (b & (NFLAG - 1));
    while (__hip_atomic_load(flag, __ATOMIC_RELAXED, AGENT) < g)
      __builtin_amdgcn_s_sleep(1);
    (void)__hip_atomic_load(flag, __ATOMIC_ACQUIRE, AGENT);
  }
  __syncthreads();
}

__global__ void __launch_bounds__(NT, 4) predcells(
    const float* __restrict__ inp,
    const float* __restrict__ W0w, const float* __restrict__ W0b,
    const float* __restrict__ W1w, const float* __restrict__ W1b,
    const float* __restrict__ W2w, const float* __restrict__ W2b,
    const float* __restrict__ Wi1, const float* __restrict__ b1,
    const float* __restrict__ Wi2, const float* __restrict__ b2,
    const float* __restrict__ Wi3, const float* __restrict__ b3,
    const float* __restrict__ V1w, const float* __restrict__ V1b,
    const float* __restrict__ V2w, const float* __restrict__ V2b,
    const float* __restrict__ V3w, const float* __restrict__ V3b,
    const int* __restrict__ itn,
    float* __restrict__ out, int* iws, float* fws)
{
  const int tid = threadIdx.x;
  const int lane = tid & 63;
  const int wv = tid >> 6;
  const int b = blockIdx.x;

  float* TD1 = fws;            // 1024
  float* TD2 = fws + 1024;     // 1024
  float* recon1 = fws + 2048;  // 64 (56 used)
  float* recon2 = fws + 2112;  // 1024
  float* recon3 = fws + 3136;  // 1024
  float* BU0 = fws + 4160;     // 1024
  float* s1  = fws + 5184;     // 1024
  float* BU1 = fws + 6208;     // 1024
  float* s2  = fws + 7232;     // 1024
  float* BU2 = fws + 8256;     // 1024
  float* s3  = fws + 9280;     // 1024

  __shared__ __align__(16) float lv[2048];
  __shared__ float ps[4][4];
  float4* lvw = (float4*)lv;
  const float4* lv4 = (const float4*)lv;

  const float lam = (itn[0] <= 1000) ? 1e-4f : 1e-2f;
  const float lam2 = lam * lam;
  float loss = 0.f;

  // ---- preloop: block0 zeroes carries + barrier state; every block computes BU0 for t=0
  if (b == 0) {
    for (int i = tid; i < 4160; i += NT) fws[i] = 0.f;  // TD1,TD2,recon1..3
    for (int i = tid; i < 2304; i += NT) if (i > 0) iws[i] = 0;
    __syncthreads();
    if (tid == 0) __hip_atomic_store(iws, 0x5D17C0DE, __ATOMIC_RELEASE, AGENT);
  }
  // BU0(t=0): nTD0 = x_0 (recon1 is zero) — does not touch fws
  if (wv == 0) {
    float acc = 0.f, ls = 0.f;
    if (lane < 14) {
      const float4 a  = ((const float4*)(W0w + b * CC))[lane];
      const float4 xv = ((const float4*)inp)[lane];
      acc = dot4(a, xv);
      ls = fabsf(xv.x) + fabsf(xv.y) + fabsf(xv.z) + fabsf(xv.w);
    }
    acc = wredsum(acc);
    ls = wredsum(ls);
    if (lane == 0) BU0[b] = acc + W0b[b];
    if (b == 0) loss += ls;
  }
  if (tid == 0) {
    while (__hip_atomic_load(iws, __ATOMIC_ACQUIRE, AGENT) != 0x5D17C0DE)
      __builtin_amdgcn_s_sleep(1);
  }
  int g = 0;
  gbar(iws, ++g, b);

  const int i2 = wv * 128 + lane;  // float4 index for L=2048 col-split
  const int i1 = wv * 64 + lane;   // float4 index for L=1024 col-split

  for (int t = 0; t < TT; ++t) {
    // ---- A: s1 = lstm(Wi1 @ [BU0;TD1] + b1)
    {
      lvw[tid]       = ((const float4*)BU0)[tid];
      lvw[256 + tid] = ((const float4*)TD1)[tid];
      __syncthreads();
      const float4* wi = (const float4*)(Wi1 + (size_t)b * 2048);
      const float4* wg = (const float4*)(Wi1 + (size_t)(b + 2048) * 2048);
      const float4* wo = (const float4*)(Wi1 + (size_t)(b + 3072) * 2048);
      float4 ai0 = wi[i2], ai1 = wi[i2 + 64];
      float4 ag0 = wg[i2], ag1 = wg[i2 + 64];
      float4 ao0 = wo[i2], ao1 = wo[i2 + 64];
      float4 v0 = lv4[i2], v1 = lv4[i2 + 64];
      float zi = wredsum(dot4(ai0, v0) + dot4(ai1, v1));
      float zg = wredsum(dot4(ag0, v0) + dot4(ag1, v1));
      float zo = wredsum(dot4(ao0, v0) + dot4(ao1, v1));
      if (lane == 0) { ps[0][wv] = zi; ps[1][wv] = zg; ps[2][wv] = zo; }
      __syncthreads();
      if (tid == 0) {
        float ZI = ps[0][0] + ps[0][1] + ps[0][2] + ps[0][3] + b1[b];
        float ZG = ps[1][0] + ps[1][1] + ps[1][2] + ps[1][3] + b1[b + 2048];
        float ZO = ps[2][0] + ps[2][1] + ps[2][2] + ps[2][3] + b1[b + 3072];
        s1[b] = sigm(ZO) * ftanh(sigm(ZI) * ftanh(ZG));
      }
    }
    gbar(iws, ++g, b);

    // ---- B: nTD1 = s1-recon2; BU1 = W1@nTD1+b; recon1 = V1@s1+b; TD1<-nTD1; loss += lam*|nTD1|
    {
      const float4 sv = ((const float4*)s1)[tid];
      const float4 rv = ((const float4*)recon2)[tid];
      float4 d; d.x = sv.x - rv.x; d.y = sv.y - rv.y; d.z = sv.z - rv.z; d.w = sv.w - rv.w;
      lvw[tid] = d;
      lvw[256 + tid] = sv;
      if (b == 0) ((float4*)TD1)[tid] = d;
      __syncthreads();
      const float4* w = (const float4*)(W1w + (size_t)b * 1024);
      float pw = wredsum(dot4(w[i1], lv4[i1]));
      if (lane == 0) ps[0][wv] = pw;
      const int vb = b - 512;
      if (vb >= 0 && vb < CC) {
        const float4* vw = (const float4*)(V1w + (size_t)vb * 1024);
        float pv = wredsum(dot4(vw[i1], lv4[256 + i1]));
        if (lane == 0) ps[1][wv] = pv;
      }
      __syncthreads();
      if (tid == 0) {
        BU1[b] = ps[0][0] + ps[0][1] + ps[0][2] + ps[0][3] + W1b[b];
        if (vb >= 0 && vb < CC)
          recon1[vb] = ps[1][0] + ps[1][1] + ps[1][2] + ps[1][3] + V1b[vb];
      }
      if (b == 0 && wv == 0) {
        float s = 0.f;
        for (int i = lane; i < 256; i += 64) {
          float4 dd = lv4[i];
          s += fabsf(dd.x) + fabsf(dd.y) + fabsf(dd.z) + fabsf(dd.w);
        }
        loss += lam * wredsum(s);
      }
    }
    gbar(iws, ++g, b);

    // ---- C: s2 = lstm(Wi2 @ [BU1;TD2] + b2)
    {
      lvw[tid]       = ((const float4*)BU1)[tid];
      lvw[256 + tid] = ((const float4*)TD2)[tid];
      __syncthreads();
      const float4* wi = (const float4*)(Wi2 + (size_t)b * 2048);
      const float4* wg = (const float4*)(Wi2 + (size_t)(b + 2048) * 2048);
      const float4* wo = (const float4*)(Wi2 + (size_t)(b + 3072) * 2048);
      float4 ai0 = wi[i2], ai1 = wi[i2 + 64];
      float4 ag0 = wg[i2], ag1 = wg[i2 + 64];
      float4 ao0 = wo[i2], ao1 = wo[i2 + 64];
      float4 v0 = lv4[i2], v1 = lv4[i2 + 64];
      float zi = wredsum(dot4(ai0, v0) + dot4(ai1, v1));
      float zg = wredsum(dot4(ag0, v0) + dot4(ag1, v1));
      float zo = wredsum(dot4(ao0, v0) + dot4(ao1, v1));
      if (lane == 0) { ps[0][wv] = zi; ps[1][wv] = zg; ps[2][wv] = zo; }
      __syncthreads();
      if (tid == 0) {
        float ZI = ps[0][0] + ps[0][1] + ps[0][2] + ps[0][3] + b2[b];
        float ZG = ps[1][0] + ps[1][1] + ps[1][2] + ps[1][3] + b2[b + 2048];
        float ZO = ps[2][0] + ps[2][1] + ps[2][2] + ps[2][3] + b2[b + 3072];
        s2[b] = sigm(ZO) * ftanh(sigm(ZI) * ftanh(ZG));
      }
    }
    gbar(iws, ++g, b);

    // ---- D: nTD2 = s2-recon3; BU2 = W2@nTD2+b; recon2 = V2@s2+b; TD2<-nTD2; loss += lam2*|nTD2|
    {
      const float4 sv = ((const float4*)s2)[tid];
      const float4 rv = ((const float4*)recon3)[tid];
      float4 d; d.x = sv.x - rv.x; d.y = sv.y - rv.y; d.z = sv.z - rv.z; d.w = sv.w - rv.w;
      lvw[tid] = d;
      lvw[256 + tid] = sv;
      if (b == 0) ((float4*)TD2)[tid] = d;
      __syncthreads();
      const float4* w = (const float4*)(W2w + (size_t)b * 1024);
      const float4* vw = (const float4*)(V2w + (size_t)b * 1024);
      float pw = wredsum(dot4(w[i1], lv4[i1]));
      float pv = wredsum(dot4(vw[i1], lv4[256 + i1]));
      if (lane == 0) { ps[0][wv] = pw; ps[1][wv] = pv; }
      __syncthreads();
      if (tid == 0) {
        BU2[b]    = ps[0][0] + ps[0][1] + ps[0][2] + ps[0][3] + W2b[b];
        recon2[b] = ps[1][0] + ps[1][1] + ps[1][2] + ps[1][3] + V2b[b];
      }
      if (b == 0 && wv == 0) {
        float s = 0.f;
        for (int i = lane; i < 256; i += 64) {
          float4 dd = lv4[i];
          s += fabsf(dd.x) + fabsf(dd.y) + fabsf(dd.z) + fabsf(dd.w);
        }
        loss += lam2 * wredsum(s);
      }
    }
    gbar(iws, ++g, b);

    // ---- E: s3 = lstm(Wi3 @ BU2 + b3)
    {
      lvw[tid] = ((const float4*)BU2)[tid];
      __syncthreads();
      const float4* wi = (const float4*)(Wi3 + (size_t)b * 1024);
      const float4* wg = (const float4*)(Wi3 + (size_t)(b + 2048) * 1024);
      const float4* wo = (const float4*)(Wi3 + (size_t)(b + 3072) * 1024);
      float4 v0 = lv4[i1];
      float zi = wredsum(dot4(wi[i1], v0));
      float zg = wredsum(dot4(wg[i1], v0));
      float zo = wredsum(dot4(wo[i1], v0));
      if (lane == 0) { ps[0][wv] = zi; ps[1][wv] = zg; ps[2][wv] = zo; }
      __syncthreads();
      if (tid == 0) {
        float ZI = ps[0][0] + ps[0][1] + ps[0][2] + ps[0][3] + b3[b];
        float ZG = ps[1][0] + ps[1][1] + ps[1][2] + ps[1][3] + b3[b + 2048];
        float ZO = ps[2][0] + ps[2][1] + ps[2][2] + ps[2][3] + b3[b + 3072];
        s3[b] = sigm(ZO) * ftanh(sigm(ZI) * ftanh(ZG));
      }
    }
    gbar(iws, ++g, b);

    // ---- F: recon3 = V3@s3+b ; St1(t+1): BU0 = W0@(x_{t+1}-recon1)+W0b ; loss += |nTD0|
    {
      lvw[tid] = ((const float4*)s3)[tid];
      __syncthreads();
      const float4* vw = (const float4*)(V3w + (size_t)b * 1024);
      float pv = wredsum(dot4(vw[i1], lv4[i1]));
      if (lane == 0) ps[0][wv] = pv;
      if (t < TT - 1 && wv == 1) {  // St1 for t+1 on wave 1 (whole wave active)
        float acc = 0.f, ls = 0.f;
        if (lane < 14) {
          const float4 a  = ((const float4*)(W0w + b * CC))[lane];
          const float4 xv = ((const float4*)(inp + (t + 1) * CC))[lane];
          const float4 rv = ((const float4*)recon1)[lane];
          float4 d; d.x = xv.x - rv.x; d.y = xv.y - rv.y; d.z = xv.z - rv.z; d.w = xv.w - rv.w;
          acc = dot4(a, d);
          ls = fabsf(d.x) + fabsf(d.y) + fabsf(d.z) + fabsf(d.w);
        }
        acc = wredsum(acc);   // full-wave context
        ls  = wredsum(ls);    // full-wave context (round-2 bug: was inside lane==0)
        if (lane == 0) { BU0[b] = acc + W0b[b]; ps[3][0] = ls; }
      }
      __syncthreads();
      if (tid == 0) {
        recon3[b] = ps[0][0] + ps[0][1] + ps[0][2] + ps[0][3] + V3b[b];
      }
      if (b == 0 && t < TT - 1 && wv == 0 && lane == 0) loss += ps[3][0];
    }
    gbar(iws, ++g, b);
  }

  if (b == 0 && tid == 0) out[0] = loss;
}

extern "C" void kernel_launch(void* const* d_in, const int* in_sizes, int n_in,
                              void* d_out, int out_size, void* d_ws, size_t ws_size,
                              hipStream_t stream) {
  const float* inp = (const float*)d_in[0];
  const float* W0w = (const float*)d_in[1];
  const float* W0b = (const float*)d_in[2];
  const float* W1w = (const float*)d_in[3];
  const float* W1b = (const float*)d_in[4];
  const float* W2w = (const float*)d_in[5];
  const float* W2b = (const float*)d_in[6];
  const float* Wi1 = (const float*)d_in[7];
  const float* b1  = (const float*)d_in[8];
  const float* Wi2 = (const float*)d_in[9];
  const float* b2  = (const float*)d_in[10];
  const float* Wi3 = (const float*)d_in[11];
  const float* b3  = (const float*)d_in[12];
  const float* V1w = (const float*)d_in[13];
  const float* V1b = (const float*)d_in[14];
  const float* V2w = (const float*)d_in[15];
  const float* V2b = (const float*)d_in[16];
  const float* V3w = (const float*)d_in[17];
  const float* V3b = (const float*)d_in[18];
  const int*   itn = (const int*)d_in[19];

  int*   iws = (int*)d_ws;
  float* fws = (float*)((char*)d_ws + 16384);

  hipLaunchKernelGGL(predcells, dim3(GRID), dim3(NT), 0, stream,
                     inp, W0w, W0b, W1w, W1b, W2w, W2b,
                     Wi1, b1, Wi2, b2, Wi3, b3,
                     V1w, V1b, V2w, V2b, V3w, V3b, itn,
                     (float*)d_out, iws, fws);
}

// Round 4
// 4630.517 us; speedup vs baseline: 2.5458x; 2.5458x over previous
//
#include <hip/hip_runtime.h>

#define HH 1024
#define CC 56
#define TT 64
#define GRID 1024
#define NT 256
#define NFLAG 64
#define SLOT_STRIDE 32                 // 128 B between arrival slots
#define FLAG_BASE (GRID * SLOT_STRIDE) // int offset of flag array
#define AGENT __HIP_MEMORY_SCOPE_AGENT

__device__ __forceinline__ float wredsum(float v) {
#pragma unroll
  for (int m = 32; m; m >>= 1) v += __shfl_xor(v, m, 64);
  return v;
}

__device__ __forceinline__ float sigm(float x) { return 1.f / (1.f + __expf(-x)); }
__device__ __forceinline__ float ftanh(float x) {
  x = fminf(15.f, fmaxf(-15.f, x));
  float e = __expf(2.f * x);
  return (e - 1.f) / (e + 1.f);
}
__device__ __forceinline__ float dot4(float4 a, float4 b) {
  return fmaf(a.x, b.x, fmaf(a.y, b.y, fmaf(a.z, b.z, a.w * b.w)));
}

// ---- coherent (agent-scope, L2-bypassing) accessors for cross-block data ----
__device__ __forceinline__ float2 cld2(const float* p) {
  unsigned long long u = __hip_atomic_load((const unsigned long long*)p, __ATOMIC_RELAXED, AGENT);
  union { unsigned long long u; float2 f; } c; c.u = u; return c.f;
}
__device__ __forceinline__ float4 cld4(const float* p) {
  float2 a = cld2(p), b = cld2(p + 2);
  return make_float4(a.x, a.y, b.x, b.y);
}
__device__ __forceinline__ void cst1(float* p, float v) {
  __hip_atomic_store((unsigned int*)p, __float_as_uint(v), __ATOMIC_RELAXED, AGENT);
}
__device__ __forceinline__ void cst2(float* p, float a, float b) {
  union { unsigned long long u; float2 f; } c; c.f = make_float2(a, b);
  __hip_atomic_store((unsigned long long*)p, c.u, __ATOMIC_RELAXED, AGENT);
}

// ---- RMW-free grid barrier: slot-store arrivals + block0 master poll + flag fanout.
// Slots/flags need no init: 0xAA poison is negative, g is monotonically positive.
__device__ __forceinline__ void gbar(int* iws, int g, int b) {
  __syncthreads();  // per-wave vmcnt(0): all of this block's coherent stores are at the coherence point
  if (threadIdx.x == 0)
    __hip_atomic_store(iws + SLOT_STRIDE * b, g, __ATOMIC_RELEASE, AGENT);
  if (b == 0) {  // master: 256 threads poll 4 slots each, in parallel
    for (int k = threadIdx.x; k < GRID; k += NT)
      while (__hip_atomic_load(iws + SLOT_STRIDE * k, __ATOMIC_RELAXED, AGENT) < g)
        __builtin_amdgcn_s_sleep(1);
    __syncthreads();
    if (threadIdx.x < NFLAG)
      __hip_atomic_store(iws + FLAG_BASE + 32 * threadIdx.x, g, __ATOMIC_RELEASE, AGENT);
  }
  if (threadIdx.x == 0)
    while (__hip_atomic_load(iws + FLAG_BASE + 32 * (b & (NFLAG - 1)), __ATOMIC_RELAXED, AGENT) < g)
      __builtin_amdgcn_s_sleep(1);
  __syncthreads();
}

__global__ void __launch_bounds__(NT, 4) predcells(
    const float* __restrict__ inp,
    const float* __restrict__ W0w, const float* __restrict__ W0b,
    const float* __restrict__ W1w, const float* __restrict__ W1b,
    const float* __restrict__ W2w, const float* __restrict__ W2b,
    const float* __restrict__ Wi1, const float* __restrict__ b1,
    const float* __restrict__ Wi2, const float* __restrict__ b2,
    const float* __restrict__ Wi3, const float* __restrict__ b3,
    const float* __restrict__ V1w, const float* __restrict__ V1b,
    const float* __restrict__ V2w, const float* __restrict__ V2b,
    const float* __restrict__ V3w, const float* __restrict__ V3b,
    const int* __restrict__ itn,
    float* __restrict__ out, int* iws, float* fws)
{
  const int tid = threadIdx.x;
  const int lane = tid & 63;
  const int wv = tid >> 6;
  const int b = blockIdx.x;

  // cross-block vectors (ALL accesses via cld/cst coherent atomics)
  float* TD1 = fws;            // 1024
  float* TD2 = fws + 1024;     // 1024
  float* recon1 = fws + 2048;  // 64 (56 used)
  float* recon2 = fws + 2112;  // 1024
  float* recon3 = fws + 3136;  // 1024
  float* BU0 = fws + 4160;     // 1024
  float* s1  = fws + 5184;     // 1024
  float* BU1 = fws + 6208;     // 1024
  float* s2  = fws + 7232;     // 1024
  float* BU2 = fws + 8256;     // 1024
  float* s3  = fws + 9280;     // 1024

  __shared__ float ps[4][4];   // cross-wave partial combine

  const float lam = (itn[0] <= 1000) ? 1e-4f : 1e-2f;
  const float lam2 = lam * lam;
  float loss = 0.f;  // lives in block0 tid0 only

  // ---- preloop: block0 zeroes carries (coherent stores); all blocks compute BU0(t=0)
  if (b == 0) {
    for (int i = tid * 2; i < 4160; i += NT * 2) cst2(fws + i, 0.f, 0.f);
  }
  if (wv == 0) {  // nTD0(t=0) = x_0 (recon1 is zero)
    float acc = 0.f, ls = 0.f;
    if (lane < 14) {
      const float4 a  = ((const float4*)(W0w + b * CC))[lane];
      const float4 xv = ((const float4*)inp)[lane];
      acc = dot4(a, xv);
      ls = fabsf(xv.x) + fabsf(xv.y) + fabsf(xv.z) + fabsf(xv.w);
    }
    acc = wredsum(acc);
    ls  = wredsum(ls);
    if (lane == 0) cst1(&BU0[b], acc + W0b[b]);
    if (b == 0 && lane == 0) loss += ls;
  }
  int g = 0;
  gbar(iws, ++g, b);

  const int i2 = wv * 128 + lane;  // float4 idx for L=2048 weight rows

  for (int t = 0; t < TT; ++t) {
    // ---- A: s1 = lstm(Wi1 @ [BU0;TD1] + b1)
    {
      const float* srcA = (wv < 2) ? BU0 : TD1;  // wave-uniform
      const int bse = ((wv & 1) * 128 + lane) * 4;
      float4 v0 = cld4(srcA + bse);
      float4 v1 = cld4(srcA + bse + 256);
      const float4* wi = (const float4*)(Wi1 + (size_t)b * 2048);
      const float4* wg = (const float4*)(Wi1 + (size_t)(b + 2048) * 2048);
      const float4* wo = (const float4*)(Wi1 + (size_t)(b + 3072) * 2048);
      float zi = wredsum(dot4(wi[i2], v0) + dot4(wi[i2 + 64], v1));
      float zg = wredsum(dot4(wg[i2], v0) + dot4(wg[i2 + 64], v1));
      float zo = wredsum(dot4(wo[i2], v0) + dot4(wo[i2 + 64], v1));
      if (lane == 0) { ps[0][wv] = zi; ps[1][wv] = zg; ps[2][wv] = zo; }
      __syncthreads();
      if (tid == 0) {
        float ZI = ps[0][0] + ps[0][1] + ps[0][2] + ps[0][3] + b1[b];
        float ZG = ps[1][0] + ps[1][1] + ps[1][2] + ps[1][3] + b1[b + 2048];
        float ZO = ps[2][0] + ps[2][1] + ps[2][2] + ps[2][3] + b1[b + 3072];
        cst1(&s1[b], sigm(ZO) * ftanh(sigm(ZI) * ftanh(ZG)));
      }
    }
    gbar(iws, ++g, b);

    // ---- B: nTD1 = s1-recon2; BU1 = W1@nTD1+b; recon1 = V1@s1+b; TD1<-nTD1; loss += lam*|nTD1|
    {
      float4 sv = cld4(s1 + tid * 4);
      float4 rv = cld4(recon2 + tid * 4);
      float4 d = make_float4(sv.x - rv.x, sv.y - rv.y, sv.z - rv.z, sv.w - rv.w);
      const float4* w = (const float4*)(W1w + (size_t)b * 1024);
      float pw = wredsum(dot4(w[tid], d));
      if (lane == 0) ps[0][wv] = pw;
      const int vb = b - 512;
      if (vb >= 0 && vb < CC) {
        const float4* vw = (const float4*)(V1w + (size_t)vb * 1024);
        float pv = wredsum(dot4(vw[tid], sv));
        if (lane == 0) ps[1][wv] = pv;
      }
      if (b == 0) {
        cst2(TD1 + tid * 4, d.x, d.y);
        cst2(TD1 + tid * 4 + 2, d.z, d.w);
        float l = fabsf(d.x) + fabsf(d.y) + fabsf(d.z) + fabsf(d.w);
        l = wredsum(l);
        if (lane == 0) ps[2][wv] = l;
      }
      __syncthreads();
      if (tid == 0) {
        cst1(&BU1[b], ps[0][0] + ps[0][1] + ps[0][2] + ps[0][3] + W1b[b]);
        if (vb >= 0 && vb < CC)
          cst1(&recon1[vb], ps[1][0] + ps[1][1] + ps[1][2] + ps[1][3] + V1b[vb]);
        if (b == 0) loss += lam * (ps[2][0] + ps[2][1] + ps[2][2] + ps[2][3]);
      }
    }
    gbar(iws, ++g, b);

    // ---- C: s2 = lstm(Wi2 @ [BU1;TD2] + b2)
    {
      const float* srcC = (wv < 2) ? BU1 : TD2;
      const int bse = ((wv & 1) * 128 + lane) * 4;
      float4 v0 = cld4(srcC + bse);
      float4 v1 = cld4(srcC + bse + 256);
      const float4* wi = (const float4*)(Wi2 + (size_t)b * 2048);
      const float4* wg = (const float4*)(Wi2 + (size_t)(b + 2048) * 2048);
      const float4* wo = (const float4*)(Wi2 + (size_t)(b + 3072) * 2048);
      float zi = wredsum(dot4(wi[i2], v0) + dot4(wi[i2 + 64], v1));
      float zg = wredsum(dot4(wg[i2], v0) + dot4(wg[i2 + 64], v1));
      float zo = wredsum(dot4(wo[i2], v0) + dot4(wo[i2 + 64], v1));
      if (lane == 0) { ps[0][wv] = zi; ps[1][wv] = zg; ps[2][wv] = zo; }
      __syncthreads();
      if (tid == 0) {
        float ZI = ps[0][0] + ps[0][1] + ps[0][2] + ps[0][3] + b2[b];
        float ZG = ps[1][0] + ps[1][1] + ps[1][2] + ps[1][3] + b2[b + 2048];
        float ZO = ps[2][0] + ps[2][1] + ps[2][2] + ps[2][3] + b2[b + 3072];
        cst1(&s2[b], sigm(ZO) * ftanh(sigm(ZI) * ftanh(ZG)));
      }
    }
    gbar(iws, ++g, b);

    // ---- D: nTD2 = s2-recon3; BU2 = W2@nTD2+b; recon2 = V2@s2+b; TD2<-nTD2; loss += lam2*|nTD2|
    {
      float4 sv = cld4(s2 + tid * 4);
      float4 rv = cld4(recon3 + tid * 4);
      float4 d = make_float4(sv.x - rv.x, sv.y - rv.y, sv.z - rv.z, sv.w - rv.w);
      const float4* w  = (const float4*)(W2w + (size_t)b * 1024);
      const float4* vw = (const float4*)(V2w + (size_t)b * 1024);
      float pw = wredsum(dot4(w[tid], d));
      float pv = wredsum(dot4(vw[tid], sv));
      if (lane == 0) { ps[0][wv] = pw; ps[1][wv] = pv; }
      if (b == 0) {
        cst2(TD2 + tid * 4, d.x, d.y);
        cst2(TD2 + tid * 4 + 2, d.z, d.w);
        float l = fabsf(d.x) + fabsf(d.y) + fabsf(d.z) + fabsf(d.w);
        l = wredsum(l);
        if (lane == 0) ps[2][wv] = l;
      }
      __syncthreads();
      if (tid == 0) {
        cst1(&BU2[b],    ps[0][0] + ps[0][1] + ps[0][2] + ps[0][3] + W2b[b]);
        cst1(&recon2[b], ps[1][0] + ps[1][1] + ps[1][2] + ps[1][3] + V2b[b]);
        if (b == 0) loss += lam2 * (ps[2][0] + ps[2][1] + ps[2][2] + ps[2][3]);
      }
    }
    gbar(iws, ++g, b);

    // ---- E: s3 = lstm(Wi3 @ BU2 + b3)
    {
      float4 v0 = cld4(BU2 + tid * 4);
      const float4* wi = (const float4*)(Wi3 + (size_t)b * 1024);
      const float4* wg = (const float4*)(Wi3 + (size_t)(b + 2048) * 1024);
      const float4* wo = (const float4*)(Wi3 + (size_t)(b + 3072) * 1024);
      float zi = wredsum(dot4(wi[tid], v0));
      float zg = wredsum(dot4(wg[tid], v0));
      float zo = wredsum(dot4(wo[tid], v0));
      if (lane == 0) { ps[0][wv] = zi; ps[1][wv] = zg; ps[2][wv] = zo; }
      __syncthreads();
      if (tid == 0) {
        float ZI = ps[0][0] + ps[0][1] + ps[0][2] + ps[0][3] + b3[b];
        float ZG = ps[1][0] + ps[1][1] + ps[1][2] + ps[1][3] + b3[b + 2048];
        float ZO = ps[2][0] + ps[2][1] + ps[2][2] + ps[2][3] + b3[b + 3072];
        cst1(&s3[b], sigm(ZO) * ftanh(sigm(ZI) * ftanh(ZG)));
      }
    }
    gbar(iws, ++g, b);

    // ---- F: recon3 = V3@s3+b ; BU0(t+1) = W0@(x_{t+1}-recon1)+W0b ; loss += |nTD0|
    {
      float4 v0 = cld4(s3 + tid * 4);
      const float4* vw = (const float4*)(V3w + (size_t)b * 1024);
      float pv = wredsum(dot4(vw[tid], v0));
      if (lane == 0) ps[0][wv] = pv;
      if (t < TT - 1 && wv == 1) {
        float acc = 0.f, ls = 0.f;
        if (lane < 14) {
          const float4 a  = ((const float4*)(W0w + b * CC))[lane];
          const float4 xv = ((const float4*)(inp + (t + 1) * CC))[lane];
          float4 rv = cld4(recon1 + lane * 4);
          float4 dd = make_float4(xv.x - rv.x, xv.y - rv.y, xv.z - rv.z, xv.w - rv.w);
          acc = dot4(a, dd);
          ls = fabsf(dd.x) + fabsf(dd.y) + fabsf(dd.z) + fabsf(dd.w);
        }
        acc = wredsum(acc);  // full-wave context
        ls  = wredsum(ls);
        if (lane == 0) { cst1(&BU0[b], acc + W0b[b]); ps[1][0] = ls; }
      }
      __syncthreads();
      if (tid == 0) {
        cst1(&recon3[b], ps[0][0] + ps[0][1] + ps[0][2] + ps[0][3] + V3b[b]);
        if (b == 0 && t < TT - 1) loss += ps[1][0];
      }
    }
    gbar(iws, ++g, b);
  }

  if (b == 0 && tid == 0) out[0] = loss;
}

extern "C" void kernel_launch(void* const* d_in, const int* in_sizes, int n_in,
                              void* d_out, int out_size, void* d_ws, size_t ws_size,
                              hipStream_t stream) {
  const float* inp = (const float*)d_in[0];
  const float* W0w = (const float*)d_in[1];
  const float* W0b = (const float*)d_in[2];
  const float* W1w = (const float*)d_in[3];
  const float* W1b = (const float*)d_in[4];
  const float* W2w = (const float*)d_in[5];
  const float* W2b = (const float*)d_in[6];
  const float* Wi1 = (const float*)d_in[7];
  const float* b1  = (const float*)d_in[8];
  const float* Wi2 = (const float*)d_in[9];
  const float* b2  = (const float*)d_in[10];
  const float* Wi3 = (const float*)d_in[11];
  const float* b3  = (const float*)d_in[12];
  const float* V1w = (const float*)d_in[13];
  const float* V1b = (const float*)d_in[14];
  const float* V2w = (const float*)d_in[15];
  const float* V2b = (const float*)d_in[16];
  const float* V3w = (const float*)d_in[17];
  const float* V3b = (const float*)d_in[18];
  const int*   itn = (const int*)d_in[19];

  int*   iws = (int*)d_ws;                          // slots + flags: 139264 B
  float* fws = (float*)((char*)d_ws + 143360);      // carry/stage vectors

  hipLaunchKernelGGL(predcells, dim3(GRID), dim3(NT), 0, stream,
                     inp, W0w, W0b, W1w, W1b, W2w, W2b,
                     Wi1, b1, Wi2, b2, Wi3, b3,
                     V1w, V1b, V2w, V2b, V3w, V3b, itn,
                     (float*)d_out, iws, fws);
}

// Round 5
// 1922.850 us; speedup vs baseline: 6.1307x; 2.4082x over previous
//
#include <hip/hip_runtime.h>

#define CC 56
#define TT 64
#define GRID 1024
#define NT 256
#define NFLAG 64
#define SS 32                    // 128 B stride between sync slots
#define FB (GRID * SS)           // flag base (int index)
#define AGENT __HIP_MEMORY_SCOPE_AGENT

static __device__ __forceinline__ float wredsum(float v) {
#pragma unroll
  for (int m = 32; m; m >>= 1) v += __shfl_xor(v, m, 64);
  return v;
}
static __device__ __forceinline__ float sigm(float x) { return 1.f / (1.f + __expf(-x)); }
static __device__ __forceinline__ float ftanh(float x) {
  x = fminf(15.f, fmaxf(-15.f, x));
  float e = __expf(2.f * x);
  return (e - 1.f) / (e + 1.f);
}
static __device__ __forceinline__ float dot4(float4 a, float4 b) {
  return fmaf(a.x, b.x, fmaf(a.y, b.y, fmaf(a.z, b.z, a.w * b.w)));
}

// coherent (agent-scope write-through) accessors for cross-block data
static __device__ __forceinline__ float2 cld2(const float* p) {
  unsigned long long u = __hip_atomic_load((const unsigned long long*)p, __ATOMIC_RELAXED, AGENT);
  union { unsigned long long u; float2 f; } c; c.u = u; return c.f;
}
static __device__ __forceinline__ float4 cld4(const float* p) {
  float2 a = cld2(p), b = cld2(p + 2);
  return make_float4(a.x, a.y, b.x, b.y);
}
static __device__ __forceinline__ void cst1(float* p, float v) {
  __hip_atomic_store((unsigned int*)p, __float_as_uint(v), __ATOMIC_RELAXED, AGENT);
}
static __device__ __forceinline__ void cst2(float* p, float a, float b) {
  union { unsigned long long u; float2 f; } c; c.f = make_float2(a, b);
  __hip_atomic_store((unsigned long long*)p, c.u, __ATOMIC_RELAXED, AGENT);
}
static __device__ __forceinline__ int ldi(const int* p) {
  return __hip_atomic_load(p, __ATOMIC_RELAXED, AGENT);
}
static __device__ __forceinline__ void sti(int* p, int v) {
  __hip_atomic_store(p, v, __ATOMIC_RELAXED, AGENT);
}

// ---- all-relaxed split barrier. Slots/flags need no init (0xAA poison < 0, g > 0 monotone).
// Ordering: __syncthreads drains vmcnt(0) (write-through stores at coherence point) before arrival.
static __device__ __forceinline__ void warr(int* iws, int g, int b) {
  __syncthreads();
  if (threadIdx.x == 0) sti(iws + SS * b, g);
}
static __device__ __forceinline__ void wwait(int* iws, int g, int b) {
  if (b == 0) {  // master: batched poll, 4 independent loads per sweep; no flag spin
    const int* p0 = iws + SS * threadIdx.x;
    for (;;) {
      int a0 = ldi(p0), a1 = ldi(p0 + SS * 256), a2 = ldi(p0 + SS * 512), a3 = ldi(p0 + SS * 768);
      if (a0 >= g && a1 >= g && a2 >= g && a3 >= g) break;
      __builtin_amdgcn_s_sleep(1);
    }
    __syncthreads();
    if (threadIdx.x < NFLAG) sti(iws + FB + SS * threadIdx.x, g);
  } else {
    if (threadIdx.x == 0)
      while (ldi(iws + FB + SS * (b & (NFLAG - 1))) < g) __builtin_amdgcn_s_sleep(1);
  }
  __asm__ __volatile__("" ::: "memory");  // no load hoisting above the spin
  __syncthreads();
}

__global__ void __launch_bounds__(NT, 4) predcells(
    const float* __restrict__ inp,
    const float* __restrict__ W0w, const float* __restrict__ W0b,
    const float* __restrict__ W1w, const float* __restrict__ W1b,
    const float* __restrict__ W2w, const float* __restrict__ W2b,
    const float* __restrict__ Wi1, const float* __restrict__ b1,
    const float* __restrict__ Wi2, const float* __restrict__ b2,
    const float* __restrict__ Wi3, const float* __restrict__ b3,
    const float* __restrict__ V1w, const float* __restrict__ V1b,
    const float* __restrict__ V2w, const float* __restrict__ V2b,
    const float* __restrict__ V3w, const float* __restrict__ V3b,
    const int* __restrict__ itn,
    float* __restrict__ out, int* iws, float* fws)
{
  const int tid = threadIdx.x;
  const int lane = tid & 63;
  const int wv = tid >> 6;
  const int b = blockIdx.x;
  const int wb = b;  // row id

  float* TD1 = fws;            // 1024
  float* TD2 = fws + 1024;     // 1024
  float* recon1 = fws + 2048;  // 64 (56 used)
  float* recon2 = fws + 2112;  // 1024
  float* recon3 = fws + 3136;  // 1024
  float* BU0 = fws + 4160;     // 1024
  float* s1  = fws + 5184;     // 1024
  float* BU1 = fws + 6208;     // 1024
  float* s2  = fws + 7232;     // 1024
  float* BU2 = fws + 8256;     // 1024
  float* s3  = fws + 9280;     // 1024

  __shared__ float ps[4][4];

  const float lam = (itn[0] <= 1000) ? 1e-4f : 1e-2f;
  const float lam2 = lam * lam;
  float loss = 0.f;  // block0 tid0 only

  // ---- preloop: block0 zeroes carries; every block computes BU0(t=0)
  if (b == 0) {
    for (int i = tid * 2; i < 4160; i += NT * 2) cst2(fws + i, 0.f, 0.f);
  }
  if (wv == 0) {  // nTD0(t=0) = x_0 (recon1 zero)
    float acc = 0.f, ls = 0.f;
    if (lane < 14) {
      const float4 a  = ((const float4*)(W0w + wb * CC))[lane];
      const float4 xv = ((const float4*)inp)[lane];
      acc = dot4(a, xv);
      ls = fabsf(xv.x) + fabsf(xv.y) + fabsf(xv.z) + fabsf(xv.w);
    }
    acc = wredsum(acc);
    ls  = wredsum(ls);
    if (lane == 0) cst1(&BU0[wb], acc + W0b[wb]);
    if (b == 0 && lane == 0) loss += ls;
  }
  int g = 1;
  warr(iws, g, b);

  const int i2 = wv * 128 + lane;  // f4 idx within 2048-wide rows

  for (int t = 0; t < TT; ++t) {
    // ======== prefetch A (Wi1 rows; TD1 halves for waves 2,3) — safe: TD1 last written B_{t-1}
    float4 aA0, aA1, gA0, gA1, oA0, oA1, tdA0, tdA1;
    {
      const float4* wi = (const float4*)(Wi1 + (size_t)wb * 2048);
      const float4* wg = (const float4*)(Wi1 + (size_t)(wb + 2048) * 2048);
      const float4* wo = (const float4*)(Wi1 + (size_t)(wb + 3072) * 2048);
      aA0 = wi[i2]; aA1 = wi[i2 + 64];
      gA0 = wg[i2]; gA1 = wg[i2 + 64];
      oA0 = wo[i2]; oA1 = wo[i2 + 64];
      if (wv >= 2) {
        const int tb = ((wv - 2) * 128 + lane) * 4;
        tdA0 = cld4(TD1 + tb); tdA1 = cld4(TD1 + tb + 256);
      }
    }
    wwait(iws, g, b);
    // ---- A: s1 = lstm(Wi1 @ [BU0;TD1] + b1)
    {
      float4 v0, v1;
      if (wv < 2) {
        const int base = (wv * 128 + lane) * 4;
        v0 = cld4(BU0 + base); v1 = cld4(BU0 + base + 256);
      } else {
        v0 = tdA0; v1 = tdA1;
        if (t == 0) { v0 = make_float4(0.f, 0.f, 0.f, 0.f); v1 = v0; }  // prefetch unordered vs zeroing at t=0
      }
      float zi = wredsum(dot4(aA0, v0) + dot4(aA1, v1));
      float zg = wredsum(dot4(gA0, v0) + dot4(gA1, v1));
      float zo = wredsum(dot4(oA0, v0) + dot4(oA1, v1));
      if (lane == 0) { ps[0][wv] = zi; ps[1][wv] = zg; ps[2][wv] = zo; }
      __syncthreads();
      if (tid == 0) {
        float ZI = ps[0][0] + ps[0][1] + ps[0][2] + ps[0][3] + b1[wb];
        float ZG = ps[1][0] + ps[1][1] + ps[1][2] + ps[1][3] + b1[wb + 2048];
        float ZO = ps[2][0] + ps[2][1] + ps[2][2] + ps[2][3] + b1[wb + 3072];
        cst1(&s1[wb], sigm(ZO) * ftanh(sigm(ZI) * ftanh(ZG)));
      }
    }
    warr(iws, ++g, b);

    // ======== prefetch B (W1/V1 rows; recon2 written D_{t-1} or preloop — safe)
    float4 w1r, rv2, v1r;
    const int vb = wb - 512;
    {
      w1r = ((const float4*)(W1w + (size_t)wb * 1024))[tid];
      rv2 = cld4(recon2 + tid * 4);
      if (vb >= 0 && vb < CC) v1r = ((const float4*)(V1w + (size_t)vb * 1024))[tid];
    }
    wwait(iws, g, b);
    // ---- B: nTD1 = s1-recon2; BU1 = W1@nTD1+b; recon1 = V1@s1+b; TD1<-nTD1; loss += lam*|nTD1|
    {
      float4 sv = cld4(s1 + tid * 4);
      float4 d = make_float4(sv.x - rv2.x, sv.y - rv2.y, sv.z - rv2.z, sv.w - rv2.w);
      float pw = wredsum(dot4(w1r, d));
      if (lane == 0) ps[0][wv] = pw;
      if (vb >= 0 && vb < CC) {
        float pv = wredsum(dot4(v1r, sv));
        if (lane == 0) ps[1][wv] = pv;
      }
      if (b == 0) {
        cst2(TD1 + tid * 4, d.x, d.y);
        cst2(TD1 + tid * 4 + 2, d.z, d.w);
        float l = wredsum(fabsf(d.x) + fabsf(d.y) + fabsf(d.z) + fabsf(d.w));
        if (lane == 0) ps[2][wv] = l;
      }
      __syncthreads();
      if (tid == 0) {
        cst1(&BU1[wb], ps[0][0] + ps[0][1] + ps[0][2] + ps[0][3] + W1b[wb]);
        if (vb >= 0 && vb < CC)
          cst1(&recon1[vb], ps[1][0] + ps[1][1] + ps[1][2] + ps[1][3] + V1b[vb]);
        if (b == 0) loss += lam * (ps[2][0] + ps[2][1] + ps[2][2] + ps[2][3]);
      }
    }
    warr(iws, ++g, b);

    // ======== prefetch C (Wi2 rows; TD2 halves — written D_{t-1}/preloop, safe)
    float4 aC0, aC1, gC0, gC1, oC0, oC1, tdC0, tdC1;
    {
      const float4* wi = (const float4*)(Wi2 + (size_t)wb * 2048);
      const float4* wg = (const float4*)(Wi2 + (size_t)(wb + 2048) * 2048);
      const float4* wo = (const float4*)(Wi2 + (size_t)(wb + 3072) * 2048);
      aC0 = wi[i2]; aC1 = wi[i2 + 64];
      gC0 = wg[i2]; gC1 = wg[i2 + 64];
      oC0 = wo[i2]; oC1 = wo[i2 + 64];
      if (wv >= 2) {
        const int tb = ((wv - 2) * 128 + lane) * 4;
        tdC0 = cld4(TD2 + tb); tdC1 = cld4(TD2 + tb + 256);
      }
    }
    wwait(iws, g, b);
    // ---- C: s2 = lstm(Wi2 @ [BU1;TD2] + b2)
    {
      float4 v0, v1;
      if (wv < 2) {
        const int base = (wv * 128 + lane) * 4;
        v0 = cld4(BU1 + base); v1 = cld4(BU1 + base + 256);
      } else { v0 = tdC0; v1 = tdC1; }
      float zi = wredsum(dot4(aC0, v0) + dot4(aC1, v1));
      float zg = wredsum(dot4(gC0, v0) + dot4(gC1, v1));
      float zo = wredsum(dot4(oC0, v0) + dot4(oC1, v1));
      if (lane == 0) { ps[0][wv] = zi; ps[1][wv] = zg; ps[2][wv] = zo; }
      __syncthreads();
      if (tid == 0) {
        float ZI = ps[0][0] + ps[0][1] + ps[0][2] + ps[0][3] + b2[wb];
        float ZG = ps[1][0] + ps[1][1] + ps[1][2] + ps[1][3] + b2[wb + 2048];
        float ZO = ps[2][0] + ps[2][1] + ps[2][2] + ps[2][3] + b2[wb + 3072];
        cst1(&s2[wb], sigm(ZO) * ftanh(sigm(ZI) * ftanh(ZG)));
      }
    }
    warr(iws, ++g, b);

    // ======== prefetch D (W2/V2 rows; recon3 written F_{t-1}/preloop — safe)
    float4 w2r, v2r, rv3;
    {
      w2r = ((const float4*)(W2w + (size_t)wb * 1024))[tid];
      v2r = ((const float4*)(V2w + (size_t)wb * 1024))[tid];
      rv3 = cld4(recon3 + tid * 4);
    }
    wwait(iws, g, b);
    // ---- D: nTD2 = s2-recon3; BU2 = W2@nTD2+b; recon2 = V2@s2+b; TD2<-nTD2; loss += lam2*|nTD2|
    {
      float4 sv = cld4(s2 + tid * 4);
      float4 d = make_float4(sv.x - rv3.x, sv.y - rv3.y, sv.z - rv3.z, sv.w - rv3.w);
      float pw = wredsum(dot4(w2r, d));
      float pv = wredsum(dot4(v2r, sv));
      if (lane == 0) { ps[0][wv] = pw; ps[1][wv] = pv; }
      if (b == 0) {
        cst2(TD2 + tid * 4, d.x, d.y);
        cst2(TD2 + tid * 4 + 2, d.z, d.w);
        float l = wredsum(fabsf(d.x) + fabsf(d.y) + fabsf(d.z) + fabsf(d.w));
        if (lane == 0) ps[2][wv] = l;
      }
      __syncthreads();
      if (tid == 0) {
        cst1(&BU2[wb],    ps[0][0] + ps[0][1] + ps[0][2] + ps[0][3] + W2b[wb]);
        cst1(&recon2[wb], ps[1][0] + ps[1][1] + ps[1][2] + ps[1][3] + V2b[wb]);
        if (b == 0) loss += lam2 * (ps[2][0] + ps[2][1] + ps[2][2] + ps[2][3]);
      }
    }
    warr(iws, ++g, b);

    // ======== prefetch E (Wi3 rows)
    float4 aE, gE, oE;
    {
      aE = ((const float4*)(Wi3 + (size_t)wb * 1024))[tid];
      gE = ((const float4*)(Wi3 + (size_t)(wb + 2048) * 1024))[tid];
      oE = ((const float4*)(Wi3 + (size_t)(wb + 3072) * 1024))[tid];
    }
    wwait(iws, g, b);
    // ---- E: s3 = lstm(Wi3 @ BU2 + b3)
    {
      float4 v0 = cld4(BU2 + tid * 4);
      float zi = wredsum(dot4(aE, v0));
      float zg = wredsum(dot4(gE, v0));
      float zo = wredsum(dot4(oE, v0));
      if (lane == 0) { ps[0][wv] = zi; ps[1][wv] = zg; ps[2][wv] = zo; }
      __syncthreads();
      if (tid == 0) {
        float ZI = ps[0][0] + ps[0][1] + ps[0][2] + ps[0][3] + b3[wb];
        float ZG = ps[1][0] + ps[1][1] + ps[1][2] + ps[1][3] + b3[wb + 2048];
        float ZO = ps[2][0] + ps[2][1] + ps[2][2] + ps[2][3] + b3[wb + 3072];
        cst1(&s3[wb], sigm(ZO) * ftanh(sigm(ZI) * ftanh(ZG)));
      }
    }
    warr(iws, ++g, b);

    // ======== prefetch F (V3 row; wave1: W0 row, x_{t+1}, recon1 — recon1 written B_t, 3 barriers ago)
    float4 v3r, w0r, xnx, rc1;
    {
      v3r = ((const float4*)(V3w + (size_t)wb * 1024))[tid];
      if (wv == 1 && lane < 14) {
        const int tn = (t < TT - 1) ? (t + 1) : (TT - 1);  // clamp keeps load in-bounds; unused at t=63
        w0r = ((const float4*)(W0w + wb * CC))[lane];
        xnx = ((const float4*)(inp + tn * CC))[lane];
        rc1 = cld4(recon1 + lane * 4);
      }
    }
    wwait(iws, g, b);
    // ---- F: recon3 = V3@s3+b ; BU0(t+1) = W0@(x_{t+1}-recon1)+W0b ; loss += |nTD0|
    {
      float4 v0 = cld4(s3 + tid * 4);
      float pv = wredsum(dot4(v3r, v0));
      if (lane == 0) ps[0][wv] = pv;
      if (t < TT - 1 && wv == 1) {
        float acc = 0.f, ls = 0.f;
        if (lane < 14) {
          float4 dd = make_float4(xnx.x - rc1.x, xnx.y - rc1.y, xnx.z - rc1.z, xnx.w - rc1.w);
          acc = dot4(w0r, dd);
          ls = fabsf(dd.x) + fabsf(dd.y) + fabsf(dd.z) + fabsf(dd.w);
        }
        acc = wredsum(acc);
        ls  = wredsum(ls);
        if (lane == 0) { cst1(&BU0[wb], acc + W0b[wb]); ps[1][0] = ls; }
      }
      __syncthreads();
      if (tid == 0) {
        cst1(&recon3[wb], ps[0][0] + ps[0][1] + ps[0][2] + ps[0][3] + V3b[wb]);
        if (b == 0 && t < TT - 1) loss += ps[1][0];
      }
    }
    warr(iws, ++g, b);
  }

  if (b == 0 && tid == 0) out[0] = loss;
}

extern "C" void kernel_launch(void* const* d_in, const int* in_sizes, int n_in,
                              void* d_out, int out_size, void* d_ws, size_t ws_size,
                              hipStream_t stream) {
  const float* inp = (const float*)d_in[0];
  const float* W0w = (const float*)d_in[1];
  const float* W0b = (const float*)d_in[2];
  const float* W1w = (const float*)d_in[3];
  const float* W1b = (const float*)d_in[4];
  const float* W2w = (const float*)d_in[5];
  const float* W2b = (const float*)d_in[6];
  const float* Wi1 = (const float*)d_in[7];
  const float* b1  = (const float*)d_in[8];
  const float* Wi2 = (const float*)d_in[9];
  const float* b2  = (const float*)d_in[10];
  const float* Wi3 = (const float*)d_in[11];
  const float* b3  = (const float*)d_in[12];
  const float* V1w = (const float*)d_in[13];
  const float* V1b = (const float*)d_in[14];
  const float* V2w = (const float*)d_in[15];
  const float* V2b = (const float*)d_in[16];
  const float* V3w = (const float*)d_in[17];
  const float* V3b = (const float*)d_in[18];
  const int*   itn = (const int*)d_in[19];

  int*   iws = (int*)d_ws;                          // slots+flags: 139264 B
  float* fws = (float*)((char*)d_ws + 147456);      // carry/stage vectors

  hipLaunchKernelGGL(predcells, dim3(GRID), dim3(NT), 0, stream,
                     inp, W0w, W0b, W1w, W1b, W2w, W2b,
                     Wi1, b1, Wi2, b2, Wi3, b3,
                     V1w, V1b, V2w, V2b, V3w, V3b, itn,
                     (float*)d_out, iws, fws);
}